// Round 4
// baseline (85.115 us; speedup 1.0000x reference)
//
#include <hip/hip_runtime.h>
#include <math.h>

// PCEN: EMA over time (s=0.025) + (x/(M+eps)^0.98 + 2)^0.5 - 2^0.5
// x: [B=32, T=8192, F=128] f32 -> out same shape f32.
//
// Chunked-scan with warm-up: KK=64 chunks of CC=128. Chunks with t0<=256
// warm up from t=0 (EXACT, since M[0]=x[0] is a fixed point: a+s=1).
// Chunks with t0>256 warm up over 256 steps from m=0.5 (uniform-mean init,
// |0.5-M|<=~0.17; forgetting a^256=1.6e-3 => out err ~1e-3 << 9.5e-2).
//
// R3 -> R4: float2/lane (8B loads), NORMAL stores (nt stores serialized the
// loop on store-data register reuse: vmcnt retires at HBM), manual 8-deep
// software pipeline with explicit register rotation for loads AND stores.

#define BB 32
#define TT 8192
#define FF 128
#define KK 64
#define CC (TT / KK)   // 128
#define WW 256         // max warm-up steps
#define UU 8           // software pipeline depth
#define AA 0.975f
#define SS 0.025f

__device__ __forceinline__ float pcen_out(float xv, float m) {
    // (m+eps)^(-0.98) via v_log_f32 / v_exp_f32
    float p = __builtin_amdgcn_exp2f(-0.98f * __builtin_amdgcn_logf(m + 1e-6f));
    return sqrtf(fmaf(xv, p, 2.0f)) - 1.41421356237309505f;
}

__global__ __launch_bounds__(256) void pcen_kernel(const float* __restrict__ x,
                                                   float* __restrict__ out) {
    const int tid = threadIdx.x;
    const int row = blockIdx.x * 4 + (tid >> 6);   // 0..2047 = b*KK + k
    const int f2  = tid & 63;                      // float2 index in F
    const int b   = row >> 6;
    const int k   = row & (KK - 1);
    const int t0  = k * CC;
    const int st  = FF / 2;                        // 64 float2 per time step

    const size_t base = ((size_t)b * TT + t0) * FF + (size_t)f2 * 2;
    const float2* xp = (const float2*)(x + base);
    float2*       op = (float2*)(out + base);

    // ---- warm-up ----
    const int w = (t0 < WW) ? t0 : WW;             // 0, 128, or 256
    const float2* wp = xp - (size_t)w * st;
    float2 v0 = wp[0];
    // exact init when warm-up window reaches t=0 (t0<=WW); else mean-init.
    float m0 = (t0 > WW) ? 0.5f : v0.x;
    float m1 = (t0 > WW) ? 0.5f : v0.y;

    if (w > 0) {
        float2 buf[UU];
        #pragma unroll
        for (int u = 0; u < UU; ++u) buf[u] = wp[(size_t)u * st];
        for (int jb = 0; jb < w; jb += UU) {
            float2 v[UU];
            #pragma unroll
            for (int u = 0; u < UU; ++u) v[u] = buf[u];
            if (jb + UU < w) {
                #pragma unroll
                for (int u = 0; u < UU; ++u)
                    buf[u] = wp[(size_t)(jb + UU + u) * st];
            }
            #pragma unroll
            for (int u = 0; u < UU; ++u) {
                m0 = fmaf(AA, m0, SS * v[u].x);
                m1 = fmaf(AA, m1, SS * v[u].y);
            }
        }
    }

    // ---- main chunk: j = 0..CC-1 (j=0 recomputes exact init for t0<=WW) ----
    {
        float2 buf[UU];
        #pragma unroll
        for (int u = 0; u < UU; ++u) buf[u] = xp[(size_t)u * st];
        for (int jb = 0; jb < CC; jb += UU) {
            float2 v[UU];
            #pragma unroll
            for (int u = 0; u < UU; ++u) v[u] = buf[u];
            if (jb + UU < CC) {
                #pragma unroll
                for (int u = 0; u < UU; ++u)
                    buf[u] = xp[(size_t)(jb + UU + u) * st];
            }
            #pragma unroll
            for (int u = 0; u < UU; ++u) {
                m0 = fmaf(AA, m0, SS * v[u].x);
                m1 = fmaf(AA, m1, SS * v[u].y);
                float2 o;
                o.x = pcen_out(v[u].x, m0);
                o.y = pcen_out(v[u].y, m1);
                op[(size_t)(jb + u) * st] = o;
            }
        }
    }
}

extern "C" void kernel_launch(void* const* d_in, const int* in_sizes, int n_in,
                              void* d_out, int out_size, void* d_ws, size_t ws_size,
                              hipStream_t stream) {
    const float* x = (const float*)d_in[0];
    float* out = (float*)d_out;
    (void)in_sizes; (void)n_in; (void)out_size; (void)d_ws; (void)ws_size;
    // 2048 rows, 4 rows per 256-thread block
    pcen_kernel<<<(BB * KK) / 4, 256, 0, stream>>>(x, out);
}

// Round 5
// 74.052 us; speedup vs baseline: 1.1494x; 1.1494x over previous
//
#include <hip/hip_runtime.h>
#include <math.h>

// PCEN: EMA over time (s=0.025) + (x/(M+eps)^0.98 + 2)^0.5 - 2^0.5
// x: [B=32, T=8192, F=128] f32 -> out same shape f32.
//
// R4 -> R5: EXACT 3-pass chunked scan (no warm-up approximation).
// EMA over a chunk of C=32 is affine: M_end = a^32 * M_start + q,
// q = init-0 EMA of the chunk.
//   K1: per (b,chunk,f) compute q            -> d_ws   [reads x, 1x]
//   K2: per (b,f) serial scan of 256 carries -> d_ws in-place (q -> M_start)
//   K3: per (b,chunk,f) exact in-chunk EMA from M_start + PCEN epilogue
//       [re-reads x (L3-resident from K1), nontemporal out stores so the
//        134MB of writes don't evict x from the 256MB L3]
// 8192 rows of 1 wave each in K1/K3 = 32 waves/CU (R4 had only 8 -> latency-
// bound at 36% HBM).

#define BB 32
#define TT 8192
#define FF 128
#define CC 32            // chunk length
#define KC (TT / CC)     // 256 chunks per chain
#define AA 0.975f
#define SS 0.025f

using f32x2 = __attribute__((ext_vector_type(2))) float;

constexpr float pow_a32() {
    float p = 1.0f;
    for (int i = 0; i < 32; ++i) p *= 0.975f;
    return p;
}
constexpr float P32 = pow_a32();   // a^32

__device__ __forceinline__ float pcen_out(float xv, float m) {
    // (m+eps)^(-0.98) via v_log_f32 / v_exp_f32
    float p = __builtin_amdgcn_exp2f(-0.98f * __builtin_amdgcn_logf(m + 1e-6f));
    return sqrtf(fmaf(xv, p, 2.0f)) - 1.41421356237309505f;
}

// ---- K1: per-chunk init-0 EMA partial q (chunk 0: true value, init x[0]) ----
__global__ __launch_bounds__(256) void pcen_k1(const float* __restrict__ x,
                                               float* __restrict__ q) {
    const int tid = threadIdx.x;
    const int row = blockIdx.x * 4 + (tid >> 6);   // b*KC + k, 0..8191
    const int b   = row >> 8;
    const int k   = row & (KC - 1);
    const int f2  = tid & 63;

    const f32x2* xp = (const f32x2*)(x + ((size_t)b * TT + (size_t)k * CC) * FF) + f2;
    f32x2 v[CC];
    #pragma unroll
    for (int j = 0; j < CC; ++j) v[j] = xp[(size_t)j * (FF / 2)];

    float m0, m1;
    if (k == 0) { m0 = v[0][0];      m1 = v[0][1]; }       // M[0] = x[0]
    else        { m0 = SS * v[0][0]; m1 = SS * v[0][1]; }  // init-0 EMA
    #pragma unroll
    for (int j = 1; j < CC; ++j) {
        m0 = fmaf(AA, m0, SS * v[j][0]);
        m1 = fmaf(AA, m1, SS * v[j][1]);
    }

    f32x2* qp = (f32x2*)(q + ((size_t)b * KC + k) * FF) + f2;
    f32x2 o; o[0] = m0; o[1] = m1;
    *qp = o;
}

// ---- K2: serial scan over chunks; q[b][k][f] -> M_start[b][k][f] in place ----
__global__ __launch_bounds__(256) void pcen_k2(float* __restrict__ q) {
    const int c = blockIdx.x * 256 + threadIdx.x;  // 0..4095 = b*FF + f
    const int b = c >> 7;
    const int f = c & (FF - 1);
    float* qp = q + (size_t)b * KC * FF + f;

    float carry = 0.0f;
    for (int k0 = 0; k0 < KC; k0 += 8) {
        float t[8];
        #pragma unroll
        for (int u = 0; u < 8; ++u) t[u] = qp[(size_t)(k0 + u) * FF];
        #pragma unroll
        for (int u = 0; u < 8; ++u) {
            const int k = k0 + u;
            if (k == 0) {
                qp[0] = 0.0f;          // M_start[0] unused (K3 special-cases)
                carry = t[0];          // q[0] is the true end-of-chunk-0 M
            } else {
                qp[(size_t)k * FF] = carry;           // carry INTO chunk k
                carry = fmaf(P32, carry, t[u]);       // end of chunk k
            }
        }
    }
}

// ---- K3: exact in-chunk EMA from M_start + PCEN output ----
__global__ __launch_bounds__(256) void pcen_k3(const float* __restrict__ x,
                                               const float* __restrict__ q,
                                               float* __restrict__ out) {
    const int tid = threadIdx.x;
    const int row = blockIdx.x * 4 + (tid >> 6);
    const int b   = row >> 8;
    const int k   = row & (KC - 1);
    const int f2  = tid & 63;

    const size_t base = ((size_t)b * TT + (size_t)k * CC) * FF;
    const f32x2* xp = (const f32x2*)(x + base) + f2;
    f32x2*       op = (f32x2*)(out + base) + f2;

    f32x2 v[CC];
    #pragma unroll
    for (int j = 0; j < CC; ++j) v[j] = xp[(size_t)j * (FF / 2)];

    float m0, m1;
    if (k == 0) {
        m0 = v[0][0]; m1 = v[0][1];                        // M[0] = x[0]
    } else {
        const f32x2 mn = *((const f32x2*)(q + ((size_t)b * KC + k) * FF) + f2);
        m0 = fmaf(AA, mn[0], SS * v[0][0]);
        m1 = fmaf(AA, mn[1], SS * v[0][1]);
    }
    {
        f32x2 o; o[0] = pcen_out(v[0][0], m0); o[1] = pcen_out(v[0][1], m1);
        __builtin_nontemporal_store(o, op);
    }
    #pragma unroll
    for (int j = 1; j < CC; ++j) {
        m0 = fmaf(AA, m0, SS * v[j][0]);
        m1 = fmaf(AA, m1, SS * v[j][1]);
        f32x2 o; o[0] = pcen_out(v[j][0], m0); o[1] = pcen_out(v[j][1], m1);
        __builtin_nontemporal_store(o, op + (size_t)j * (FF / 2));
    }
}

// ---- fallback (ws too small): R2-style warm-up kernel, known-good ----
__global__ __launch_bounds__(128) void pcen_fallback(const float* __restrict__ x,
                                                     float* __restrict__ out) {
    const int job = blockIdx.x;
    const int b   = job >> 5;
    const int k   = job & 31;
    const int f   = threadIdx.x;
    const int t0  = k * 256;
    const size_t base = ((size_t)b * TT + t0) * FF + f;
    const float* xp = x + base;
    float*       op = out + base;
    float m;
    if (k == 0) {
        float xv = xp[0];
        m = xv;
        op[0] = pcen_out(xv, m);
    } else {
        const float* wp = xp - (size_t)256 * FF;
        m = wp[0];
        #pragma unroll 8
        for (int j = 1; j < 256; ++j) m = fmaf(AA, m, SS * wp[(size_t)j * FF]);
        float xv = xp[0];
        m = fmaf(AA, m, SS * xv);
        op[0] = pcen_out(xv, m);
    }
    #pragma unroll 4
    for (int j = 1; j < 256; ++j) {
        float xv = xp[(size_t)j * FF];
        m = fmaf(AA, m, SS * xv);
        op[(size_t)j * FF] = pcen_out(xv, m);
    }
}

extern "C" void kernel_launch(void* const* d_in, const int* in_sizes, int n_in,
                              void* d_out, int out_size, void* d_ws, size_t ws_size,
                              hipStream_t stream) {
    const float* x = (const float*)d_in[0];
    float* out = (float*)d_out;
    (void)in_sizes; (void)n_in; (void)out_size;

    const size_t q_bytes = (size_t)BB * KC * FF * sizeof(float);  // 4 MB
    if (ws_size >= q_bytes) {
        float* q = (float*)d_ws;
        pcen_k1<<<(BB * KC) / 4, 256, 0, stream>>>(x, q);
        pcen_k2<<<(BB * FF) / 256, 256, 0, stream>>>(q);
        pcen_k3<<<(BB * KC) / 4, 256, 0, stream>>>(x, q, out);
    } else {
        pcen_fallback<<<BB * 32, 128, 0, stream>>>(x, out);
    }
}